// Round 1
// baseline (260.664 us; speedup 1.0000x reference)
//
#include <hip/hip_runtime.h>

// Block attention with global tokens on MI355X (gfx950).
// B=4,H=16,T=4096,d=64,G=128,BLOCK=128,nb=32 -> 2048 workgroups.
// fp32-accurate via bf16 hi/lo split MFMA (3 products per GEMM term).

typedef __attribute__((ext_vector_type(8))) short bf16x8;
typedef __attribute__((ext_vector_type(4))) float f32x4;

__device__ __forceinline__ unsigned short f2bf(float x) {
    unsigned u = __float_as_uint(x);
    u = (u + 0x7FFFu + ((u >> 16) & 1u)) >> 16;
    return (unsigned short)u;
}
__device__ __forceinline__ float bf2f(unsigned short h) {
    return __uint_as_float(((unsigned)h) << 16);
}

union BF8 { bf16x8 v; unsigned short u[8]; };

// split 8 contiguous fp32 (16B-aligned) into hi/lo bf16 fragments
__device__ __forceinline__ void split8_lds(const float* p, bf16x8& hi, bf16x8& lo) {
    f32x4 a = *(const f32x4*)(p);
    f32x4 b = *(const f32x4*)(p + 4);
    BF8 H, L;
#pragma unroll
    for (int i = 0; i < 4; ++i) {
        unsigned short h0 = f2bf(a[i]);
        H.u[i] = h0; L.u[i] = f2bf(a[i] - bf2f(h0));
        unsigned short h1 = f2bf(b[i]);
        H.u[i + 4] = h1; L.u[i + 4] = f2bf(b[i] - bf2f(h1));
    }
    hi = H.v; lo = L.v;
}

#define MFMA(A, Bf, C) __builtin_amdgcn_mfma_f32_16x16x32_bf16((A), (Bf), (C), 0, 0, 0)

#define LDS_BYTES 55296

__global__ __launch_bounds__(256, 2) void block_attn_kernel(
    const float* __restrict__ q, const float* __restrict__ k,
    const float* __restrict__ v, const float* __restrict__ amask,
    const float* __restrict__ gk, const float* __restrict__ gv,
    const float* __restrict__ gmask, float* __restrict__ out) {
    constexpr int Hh = 16, Tt = 4096, Dd = 64, Gg = 128;

    __shared__ __align__(16) unsigned char lds[LDS_BYTES];
    // phase A layout
    unsigned short* q_hi = (unsigned short*)(lds);           // [128][72] bf16
    unsigned short* q_lo = (unsigned short*)(lds + 18432);   // [128][72]
    unsigned short* k_hi = (unsigned short*)(lds + 36864);   // [64][72]
    unsigned short* k_lo = (unsigned short*)(lds + 46080);   // [64][72]
    // phase B layout (aliases A; A fully dead by then)
    float*          p_ld  = (float*)(lds);                   // [128][68] fp32
    unsigned short* vt_hi = (unsigned short*)(lds + 36864);  // [64][72]  V^T
    unsigned short* vt_lo = (unsigned short*)(lds + 46080);  // [64][72]

    const int blk = blockIdx.x;
    const int h   = blockIdx.y;
    const int b   = blockIdx.z;
    const int bh  = b * Hh + h;
    const int tid  = threadIdx.x;
    const int lane = tid & 63;
    const int wv   = tid >> 6;
    const int c15  = lane & 15;
    const int quad = lane >> 4;

    const float* qptr = q + ((size_t)bh * Tt + blk * 128) * Dd;
    const float* kptr = k + ((size_t)bh * Tt + blk * 128) * Dd;
    const float* vptr = v + ((size_t)bh * Tt + blk * 128) * Dd;
    const float* gkp  = gk + (size_t)bh * Gg * Dd;
    const float* gvp  = gv + (size_t)bh * Gg * Dd;
    const float* amp  = amask + (size_t)bh * Tt + blk * 128;
    const float* gmp  = gmask + (size_t)bh * Gg;

    // ---------------- stage Q: 128x64 fp32 -> hi/lo bf16 (stride 72) ---------
    {
        const int slot = tid & 15, r0 = tid >> 4;
#pragma unroll
        for (int i = 0; i < 8; ++i) {
            int row = r0 + i * 16;
            float4 val = *reinterpret_cast<const float4*>(qptr + row * 64 + slot * 4);
            int base = row * 72 + slot * 4;
            unsigned short h0 = f2bf(val.x), h1 = f2bf(val.y), h2 = f2bf(val.z), h3 = f2bf(val.w);
            *reinterpret_cast<ushort4*>(q_hi + base) = make_ushort4(h0, h1, h2, h3);
            *reinterpret_cast<ushort4*>(q_lo + base) =
                make_ushort4(f2bf(val.x - bf2f(h0)), f2bf(val.y - bf2f(h1)),
                             f2bf(val.z - bf2f(h2)), f2bf(val.w - bf2f(h3)));
        }
    }

    f32x4 sacc[2][16];
    const f32x4 zero4 = {0.f, 0.f, 0.f, 0.f};
#pragma unroll
    for (int mt = 0; mt < 2; ++mt)
#pragma unroll
        for (int nt = 0; nt < 16; ++nt) sacc[mt][nt] = zero4;

    bf16x8 qh[2][2], ql[2][2];

    // ---------------- phase A: scores over 4 key-chunks of 64 ----------------
#pragma unroll
    for (int c = 0; c < 4; ++c) {
        if (c > 0) __syncthreads();  // prior chunk's frag reads done
        // stage K chunk c (64x64)
        {
            const float* ks = (c < 2) ? (kptr + c * 64 * 64) : (gkp + (c - 2) * 64 * 64);
            const int slot = tid & 15, r0 = tid >> 4;
#pragma unroll
            for (int i = 0; i < 4; ++i) {
                int row = r0 + i * 16;
                float4 val = *reinterpret_cast<const float4*>(ks + row * 64 + slot * 4);
                int base = row * 72 + slot * 4;
                unsigned short h0 = f2bf(val.x), h1 = f2bf(val.y), h2 = f2bf(val.z), h3 = f2bf(val.w);
                *reinterpret_cast<ushort4*>(k_hi + base) = make_ushort4(h0, h1, h2, h3);
                *reinterpret_cast<ushort4*>(k_lo + base) =
                    make_ushort4(f2bf(val.x - bf2f(h0)), f2bf(val.y - bf2f(h1)),
                                 f2bf(val.z - bf2f(h2)), f2bf(val.w - bf2f(h3)));
            }
        }
        __syncthreads();

        if (c == 0) {
            // load Q fragments once (A-layout: m=lane&15, k=quad*8+j (+32*kk))
#pragma unroll
            for (int mt = 0; mt < 2; ++mt) {
                int row = wv * 32 + mt * 16 + c15;
                qh[mt][0] = *(const bf16x8*)(q_hi + row * 72 + quad * 8);
                qh[mt][1] = *(const bf16x8*)(q_hi + row * 72 + quad * 8 + 32);
                ql[mt][0] = *(const bf16x8*)(q_lo + row * 72 + quad * 8);
                ql[mt][1] = *(const bf16x8*)(q_lo + row * 72 + quad * 8 + 32);
            }
        }

#pragma unroll
        for (int nt = 0; nt < 4; ++nt) {
            int krow = nt * 16 + c15;
            bf16x8 kh0 = *(const bf16x8*)(k_hi + krow * 72 + quad * 8);
            bf16x8 kh1 = *(const bf16x8*)(k_hi + krow * 72 + quad * 8 + 32);
            bf16x8 kl0 = *(const bf16x8*)(k_lo + krow * 72 + quad * 8);
            bf16x8 kl1 = *(const bf16x8*)(k_lo + krow * 72 + quad * 8 + 32);
#pragma unroll
            for (int mt = 0; mt < 2; ++mt) {
                f32x4 a = sacc[mt][c * 4 + nt];
                a = MFMA(qh[mt][0], kh0, a);
                a = MFMA(qh[mt][1], kh1, a);
                a = MFMA(ql[mt][0], kh0, a);
                a = MFMA(ql[mt][1], kh1, a);
                a = MFMA(qh[mt][0], kl0, a);
                a = MFMA(qh[mt][1], kl1, a);
                sacc[mt][c * 4 + nt] = a;
            }
        }
    }

    // ---------------- softmax (registers only) -------------------------------
    {
        float mv[16];
#pragma unroll
        for (int nt = 0; nt < 8; ++nt) mv[nt] = amp[nt * 16 + c15];
#pragma unroll
        for (int nt = 0; nt < 8; ++nt) mv[8 + nt] = gmp[nt * 16 + c15];

#pragma unroll
        for (int mt = 0; mt < 2; ++mt) {
#pragma unroll
            for (int r = 0; r < 4; ++r) {
                float mx = -3.4e38f;
#pragma unroll
                for (int nt = 0; nt < 16; ++nt) {
                    float s = sacc[mt][nt][r] * 0.125f + mv[nt];
                    sacc[mt][nt][r] = s;
                    mx = fmaxf(mx, s);
                }
                mx = fmaxf(mx, __shfl_xor(mx, 1));
                mx = fmaxf(mx, __shfl_xor(mx, 2));
                mx = fmaxf(mx, __shfl_xor(mx, 4));
                mx = fmaxf(mx, __shfl_xor(mx, 8));
                float sm = 0.f;
#pragma unroll
                for (int nt = 0; nt < 16; ++nt) {
                    float e = __expf(sacc[mt][nt][r] - mx);
                    sacc[mt][nt][r] = e;
                    sm += e;
                }
                sm += __shfl_xor(sm, 1);
                sm += __shfl_xor(sm, 2);
                sm += __shfl_xor(sm, 4);
                sm += __shfl_xor(sm, 8);
                float inv = 1.0f / sm;
#pragma unroll
                for (int nt = 0; nt < 16; ++nt) sacc[mt][nt][r] *= inv;
            }
        }
    }

    // ---------------- phase B: ctx = P*V over 4 key-chunks of 64 -------------
    f32x4 ctx[2][4];
#pragma unroll
    for (int mt = 0; mt < 2; ++mt)
#pragma unroll
        for (int nt = 0; nt < 4; ++nt) ctx[mt][nt] = zero4;

    __syncthreads();  // phase A LDS reads complete before overwrite
#pragma unroll
    for (int cc = 0; cc < 4; ++cc) {
        if (cc > 0) __syncthreads();
        // stage V^T chunk: V rows (64 keys) x 64 d -> vt[d][key] hi/lo
        {
            const float* vs = (cc < 2) ? (vptr + cc * 64 * 64) : (gvp + (cc - 2) * 64 * 64);
            int key = tid >> 2, c4 = tid & 3;
#pragma unroll
            for (int j = 0; j < 4; ++j) {
                int s = c4 + j * 4;
                float4 val = *reinterpret_cast<const float4*>(vs + key * 64 + s * 4);
                int d0 = s * 4;
                unsigned short h0 = f2bf(val.x), h1 = f2bf(val.y), h2 = f2bf(val.z), h3 = f2bf(val.w);
                vt_hi[(d0 + 0) * 72 + key] = h0; vt_lo[(d0 + 0) * 72 + key] = f2bf(val.x - bf2f(h0));
                vt_hi[(d0 + 1) * 72 + key] = h1; vt_lo[(d0 + 1) * 72 + key] = f2bf(val.y - bf2f(h1));
                vt_hi[(d0 + 2) * 72 + key] = h2; vt_lo[(d0 + 2) * 72 + key] = f2bf(val.z - bf2f(h2));
                vt_hi[(d0 + 3) * 72 + key] = h3; vt_lo[(d0 + 3) * 72 + key] = f2bf(val.w - bf2f(h3));
            }
        }
        // write this wave's P rows for the chunk (fp32, stride 68)
#pragma unroll
        for (int mt = 0; mt < 2; ++mt)
#pragma unroll
            for (int nt2 = 0; nt2 < 4; ++nt2)
#pragma unroll
                for (int r = 0; r < 4; ++r) {
                    int row = wv * 32 + mt * 16 + quad * 4 + r;
                    p_ld[row * 68 + nt2 * 16 + c15] = sacc[mt][cc * 4 + nt2][r];
                }
        __syncthreads();

#pragma unroll
        for (int kk = 0; kk < 2; ++kk) {
            bf16x8 ph[2], pl[2];
#pragma unroll
            for (int mt = 0; mt < 2; ++mt) {
                int row = wv * 32 + mt * 16 + c15;
                split8_lds(p_ld + row * 68 + kk * 32 + quad * 8, ph[mt], pl[mt]);
            }
#pragma unroll
            for (int ntv = 0; ntv < 4; ++ntv) {
                int vrow = ntv * 16 + c15;
                bf16x8 vh = *(const bf16x8*)(vt_hi + vrow * 72 + quad * 8 + kk * 32);
                bf16x8 vl = *(const bf16x8*)(vt_lo + vrow * 72 + quad * 8 + kk * 32);
#pragma unroll
                for (int mt = 0; mt < 2; ++mt) {
                    f32x4 a = ctx[mt][ntv];
                    a = MFMA(ph[mt], vh, a);
                    a = MFMA(pl[mt], vh, a);
                    a = MFMA(ph[mt], vl, a);
                    ctx[mt][ntv] = a;
                }
            }
        }
    }

    // ---------------- epilogue: write ctx (C/D layout: row=quad*4+r, col=c15)
    float* op = out + ((size_t)bh * Tt + blk * 128) * Dd;
#pragma unroll
    for (int mt = 0; mt < 2; ++mt)
#pragma unroll
        for (int ntv = 0; ntv < 4; ++ntv)
#pragma unroll
            for (int r = 0; r < 4; ++r) {
                int row = wv * 32 + mt * 16 + quad * 4 + r;
                op[row * 64 + ntv * 16 + c15] = ctx[mt][ntv][r];
            }
}

extern "C" void kernel_launch(void* const* d_in, const int* in_sizes, int n_in,
                              void* d_out, int out_size, void* d_ws, size_t ws_size,
                              hipStream_t stream) {
    (void)in_sizes; (void)n_in; (void)d_ws; (void)ws_size; (void)out_size;
    const float* q  = (const float*)d_in[0];
    const float* k  = (const float*)d_in[1];
    const float* v  = (const float*)d_in[2];
    const float* am = (const float*)d_in[3];
    const float* gk = (const float*)d_in[4];
    const float* gv = (const float*)d_in[5];
    const float* gm = (const float*)d_in[6];
    dim3 grid(32, 16, 4);
    block_attn_kernel<<<grid, dim3(256), 0, stream>>>(q, k, v, am, gk, gv, gm, (float*)d_out);
}